// Round 3
// baseline (254.927 us; speedup 1.0000x reference)
//
#include <hip/hip_runtime.h>

typedef __bf16 bf16;
typedef __bf16 bf16x8 __attribute__((ext_vector_type(8)));
typedef float f32x4 __attribute__((ext_vector_type(4)));

#define VOCAB 32000
#define HID 512
#define BATCH 128
#define SEQ 64

__device__ inline bf16x8 cvt8(float4 a, float4 b) {
  bf16x8 r;
  r[0] = (bf16)a.x; r[1] = (bf16)a.y; r[2] = (bf16)a.z; r[3] = (bf16)a.w;
  r[4] = (bf16)b.x; r[5] = (bf16)b.y; r[6] = (bf16)b.z; r[7] = (bf16)b.w;
  return r;
}

__device__ inline float fast_tanh(float x) {
  x = fminf(fmaxf(x, -15.f), 15.f);
  float e = __expf(2.f * x);
  return (e - 1.f) / (e + 1.f);
}
__device__ inline float fast_sig(float x) {
  return 1.f / (1.f + __expf(-x));
}

// ---------------------------------------------------------------------------
// Kernel 1: pack FULL attn_W (512 x 1024 fp32) -> bf16 MFMA-B-operand order.
//   Wp[((kchunk*32 + ntile)*64 + lane)*8 + j], lane = klane*16 + nlane.
// ---------------------------------------------------------------------------
__global__ __launch_bounds__(512) void k_pack(
    const float* __restrict__ attn_W, bf16* __restrict__ Wp) {
  int gid = blockIdx.x * 512 + threadIdx.x;  // 0..65535
  int hh = gid >> 7;                         // row h
  int kc8 = gid & 127;                       // 8-group of k
  const float* src = attn_W + (size_t)hh * 1024 + kc8 * 8;
  bf16x8 v = cvt8(((const float4*)src)[0], ((const float4*)src)[1]);
  int kchunk = kc8 >> 2, klane = kc8 & 3;
  int ntile = hh >> 4, nlane = hh & 15;
  int lane = klane * 16 + nlane;
  *(bf16x8*)(Wp + ((size_t)(kchunk * 32 + ntile) * 64 + lane) * 8) = v;
}

// ---------------------------------------------------------------------------
// Kernel 2: per-batch fused attention (e1 folded in as K=1024 GEMM).
// ---------------------------------------------------------------------------
__global__ __launch_bounds__(512) void k_attn(
    const float* __restrict__ enc, const bf16* __restrict__ Wp,
    const float* __restrict__ attn_b, const float* __restrict__ vvec,
    const float* __restrict__ emb, const int* __restrict__ ids,
    const float* __restrict__ h0, bf16* __restrict__ Acat,
    float* __restrict__ gates_ws) {
  __shared__ char smem[65536];
  __shared__ bf16 h0s[512];
  bf16* encA = (bf16*)smem;                 // phase 1: 64x512 bf16 (swizzled)
  float* spart = (float*)smem;              // phase 2: 8x64
  float* wgt = (float*)(smem + 2048);       // 64
  float* ctxp = (float*)(smem + 2304);      // 8x512

  int b = blockIdx.x, tid = threadIdx.x;
  int w = tid >> 6, lane = tid & 63;
  int l15 = lane & 15, lq = lane >> 4;
  const float* encb = enc + (size_t)b * SEQ * HID;

  // zero the gates accumulator
  {
    int gid = b * 512 + tid;
    float4 z = {0.f, 0.f, 0.f, 0.f};
    ((float4*)gates_ws)[gid] = z;
  }

  h0s[tid] = (bf16)h0[b * 512 + tid];

  // stage enc[b] -> bf16 LDS, XOR-swizzled
#pragma unroll
  for (int i = 0; i < 8; ++i) {
    int cl = tid + i * 512;
    int row = cl >> 6;
    int c = cl & 63;
    int phys = c ^ (row & 7);
    const float4* src = (const float4*)(encb + row * 512 + c * 8);
    bf16x8 v = cvt8(src[0], src[1]);
    *(bf16x8*)(encA + row * 512 + phys * 8) = v;
  }
  __syncthreads();

  f32x4 acc[4][4];
  f32x4 acc_e1[4];
#pragma unroll
  for (int mt = 0; mt < 4; ++mt)
#pragma unroll
    for (int jn = 0; jn < 4; ++jn) acc[mt][jn] = (f32x4)0.f;
#pragma unroll
  for (int jn = 0; jn < 4; ++jn) acc_e1[jn] = (f32x4)0.f;

  // h0 half: kchunks 0..15 (attn_W cols 0..511), row-invariant accumulator
#pragma unroll 4
  for (int kc = 0; kc < 16; ++kc) {
    bf16x8 af = *(const bf16x8*)(h0s + kc * 32 + lq * 8);
#pragma unroll
    for (int jn = 0; jn < 4; ++jn) {
      int nt = w * 4 + jn;
      bf16x8 bfr = *(const bf16x8*)(Wp + ((size_t)(kc * 32 + nt) * 64 + lane) * 8);
      acc_e1[jn] = __builtin_amdgcn_mfma_f32_16x16x32_bf16(af, bfr, acc_e1[jn], 0, 0, 0);
    }
  }

  // enc half: kchunks 16..31 (attn_W cols 512..1023)
#pragma unroll 2
  for (int kc = 16; kc < 32; ++kc) {
    bf16x8 bfr[4], af[4];
#pragma unroll
    for (int jn = 0; jn < 4; ++jn) {
      int nt = w * 4 + jn;
      bfr[jn] = *(const bf16x8*)(Wp + ((size_t)(kc * 32 + nt) * 64 + lane) * 8);
    }
#pragma unroll
    for (int mt = 0; mt < 4; ++mt) {
      int row = mt * 16 + l15;
      int c = (kc - 16) * 4 + lq;
      int phys = c ^ (row & 7);
      af[mt] = *(const bf16x8*)(encA + row * 512 + phys * 8);
    }
#pragma unroll
    for (int mt = 0; mt < 4; ++mt)
#pragma unroll
      for (int jn = 0; jn < 4; ++jn)
        acc[mt][jn] = __builtin_amdgcn_mfma_f32_16x16x32_bf16(
            af[mt], bfr[jn], acc[mt][jn], 0, 0, 0);
  }
  __syncthreads();  // encA dead; smem reused

  // epilogue: scores
  float p[4][4];
#pragma unroll
  for (int mt = 0; mt < 4; ++mt)
#pragma unroll
    for (int r = 0; r < 4; ++r) p[mt][r] = 0.f;
#pragma unroll
  for (int jn = 0; jn < 4; ++jn) {
    int h = (w * 4 + jn) * 16 + l15;
    float bias = attn_b[h];
    float vv = vvec[h];
#pragma unroll
    for (int mt = 0; mt < 4; ++mt)
#pragma unroll
      for (int r = 0; r < 4; ++r)
        p[mt][r] += vv * fast_tanh(acc[mt][jn][r] + acc_e1[jn][r] + bias);
  }
#pragma unroll
  for (int mt = 0; mt < 4; ++mt)
#pragma unroll
    for (int r = 0; r < 4; ++r) {
      float x = p[mt][r];
      x += __shfl_xor(x, 1);
      x += __shfl_xor(x, 2);
      x += __shfl_xor(x, 4);
      x += __shfl_xor(x, 8);
      p[mt][r] = x;
    }
  if (l15 == 0) {
#pragma unroll
    for (int mt = 0; mt < 4; ++mt)
#pragma unroll
      for (int r = 0; r < 4; ++r) {
        int s = mt * 16 + lq * 4 + r;
        spart[w * 64 + s] = p[mt][r];
      }
  }
  __syncthreads();

  // softmax over s (wave 0)
  if (tid < 64) {
    float sc = 0.f;
#pragma unroll
    for (int ww = 0; ww < 8; ++ww) sc += spart[ww * 64 + tid];
    float mx = sc;
    for (int m = 32; m; m >>= 1) mx = fmaxf(mx, __shfl_xor(mx, m));
    float e = __expf(sc - mx);
    float sm = e;
    for (int m = 32; m; m >>= 1) sm += __shfl_xor(sm, m);
    wgt[tid] = e / sm;
  }
  __syncthreads();

  // context
  {
    int hc = tid & 63, sg = tid >> 6;
    float a8[8];
#pragma unroll
    for (int j = 0; j < 8; ++j) a8[j] = 0.f;
    for (int s = sg * 8; s < sg * 8 + 8; ++s) {
      float wv = wgt[s];
      const float4* src = (const float4*)(encb + s * 512 + hc * 8);
      float4 x0 = src[0], x1 = src[1];
      a8[0] += wv * x0.x; a8[1] += wv * x0.y; a8[2] += wv * x0.z; a8[3] += wv * x0.w;
      a8[4] += wv * x1.x; a8[5] += wv * x1.y; a8[6] += wv * x1.z; a8[7] += wv * x1.w;
    }
#pragma unroll
    for (int j = 0; j < 8; ++j) ctxp[sg * 512 + hc * 8 + j] = a8[j];
  }
  __syncthreads();

  {
    int h = tid;
    float c = 0.f;
#pragma unroll
    for (int g = 0; g < 8; ++g) c += ctxp[g * 512 + h];
    int id = ids[b];
    Acat[(size_t)b * 1536 + h] = (bf16)emb[(size_t)id * 512 + h];
    Acat[(size_t)b * 1536 + 512 + h] = (bf16)c;
    Acat[(size_t)b * 1536 + 1024 + h] = (bf16)h0[b * 512 + h];
  }
}

// ---------------------------------------------------------------------------
// Kernel 3: gates partial GEMM, BARRIER-FREE. grid (32 n-tiles of 64, 6 ks).
//   Each wave loads its B-fragments directly from global (coalesced:
//   16 rows x 128 B lines); no LDS, no __syncthreads in the K-loop.
// ---------------------------------------------------------------------------
__global__ __launch_bounds__(512) void k_gates(
    const bf16* __restrict__ Acat, const float* __restrict__ W_ih,
    const float* __restrict__ W_hh, float* __restrict__ gates_ws) {
  int nb = blockIdx.x, ks = blockIdx.y;
  int tid = threadIdx.x, w = tid >> 6, lane = tid & 63;
  int l15 = lane & 15, lq = lane >> 4;
  int wm = w >> 1, wn = w & 1;  // wm 0..3 (2 mtiles), wn 0..1 (2 ntiles)

  f32x4 acc[2][2];
#pragma unroll
  for (int i = 0; i < 2; ++i)
#pragma unroll
    for (int j = 0; j < 2; ++j) acc[i][j] = (f32x4)0.f;

#pragma unroll 2
  for (int kt = 0; kt < 8; ++kt) {
    int kglob = ks * 256 + kt * 32;
    int ko = kglob + lq * 8;
    bf16x8 bfr[2], af[2];
#pragma unroll
    for (int jn = 0; jn < 2; ++jn) {
      int row = nb * 64 + (wn * 2 + jn) * 16 + l15;
      const float4* p = (kglob < 1024)
          ? (const float4*)(W_ih + (size_t)row * 1024 + ko)
          : (const float4*)(W_hh + (size_t)row * 512 + (ko - 1024));
      bfr[jn] = cvt8(p[0], p[1]);
    }
#pragma unroll
    for (int mi = 0; mi < 2; ++mi) {
      int m = (wm * 2 + mi) * 16 + l15;
      af[mi] = *(const bf16x8*)(Acat + (size_t)m * 1536 + ko);
    }
#pragma unroll
    for (int mi = 0; mi < 2; ++mi)
#pragma unroll
      for (int jn = 0; jn < 2; ++jn)
        acc[mi][jn] = __builtin_amdgcn_mfma_f32_16x16x32_bf16(
            af[mi], bfr[jn], acc[mi][jn], 0, 0, 0);
  }
#pragma unroll
  for (int mi = 0; mi < 2; ++mi)
#pragma unroll
    for (int jn = 0; jn < 2; ++jn)
#pragma unroll
      for (int rr = 0; rr < 4; ++rr) {
        int bb = (wm * 2 + mi) * 16 + lq * 4 + rr;
        int n = nb * 64 + (wn * 2 + jn) * 16 + l15;
        atomicAdd(&gates_ws[(size_t)bb * 2048 + n], acc[mi][jn][rr]);
      }
}

// ---------------------------------------------------------------------------
// Kernel 4: elementwise LSTM cell.
// ---------------------------------------------------------------------------
__global__ __launch_bounds__(512) void k_cell(
    const float* __restrict__ gates_ws, const float* __restrict__ b_ih,
    const float* __restrict__ b_hh, const float* __restrict__ c0,
    float* __restrict__ out, bf16* __restrict__ hnewb) {
  int idx = blockIdx.x * 512 + threadIdx.x;  // 0..65535
  int b = idx >> 9, h = idx & 511;
  const float* g = gates_ws + (size_t)b * 2048;
  float iv = g[h] + b_ih[h] + b_hh[h];
  float fv = g[512 + h] + b_ih[512 + h] + b_hh[512 + h];
  float gv = g[1024 + h] + b_ih[1024 + h] + b_hh[1024 + h];
  float ov = g[1536 + h] + b_ih[1536 + h] + b_hh[1536 + h];
  float cn = fast_sig(fv) * c0[idx] + fast_sig(iv) * fast_tanh(gv);
  float hn = fast_sig(ov) * fast_tanh(cn);
  out[4096000 + idx] = hn;
  out[4096000 + 65536 + idx] = cn;
  hnewb[idx] = (bf16)hn;
}

// ---------------------------------------------------------------------------
// Kernel 5: FC, BARRIER-FREE. 500 blocks x 64 vocab rows (16 waves/CU).
//   B-fragments straight from global: wave covers 16 rows x 128 B full
//   lines (perfect coalescing); fp32->bf16 convert in-register; compiler
//   pipelines loads with fine-grained vmcnt — no barrier drains.
// ---------------------------------------------------------------------------
__global__ __launch_bounds__(512) void k_fc(
    const bf16* __restrict__ hnewb, const float* __restrict__ fc_W,
    const float* __restrict__ fc_b, float* __restrict__ out) {
  int vb = blockIdx.x * 64;
  int tid = threadIdx.x, w = tid >> 6, lane = tid & 63;
  int l15 = lane & 15, lq = lane >> 4;
  int wm = w >> 1, wn = w & 1;  // wm 0..3 (2 mtiles), wn 0..1 (2 ntiles)

  f32x4 acc[2][2];
#pragma unroll
  for (int i = 0; i < 2; ++i)
#pragma unroll
    for (int j = 0; j < 2; ++j) acc[i][j] = (f32x4)0.f;

  const float* b0 = fc_W + (size_t)(vb + (wn * 2 + 0) * 16 + l15) * 512 + lq * 8;
  const float* b1 = fc_W + (size_t)(vb + (wn * 2 + 1) * 16 + l15) * 512 + lq * 8;
  const bf16* a0 = hnewb + (size_t)((wm * 2 + 0) * 16 + l15) * 512 + lq * 8;
  const bf16* a1 = hnewb + (size_t)((wm * 2 + 1) * 16 + l15) * 512 + lq * 8;

#pragma unroll 4
  for (int kt = 0; kt < 16; ++kt) {
    int ko = kt * 32;
    bf16x8 bfr[2], af[2];
    {
      const float4* p = (const float4*)(b0 + ko);
      bfr[0] = cvt8(p[0], p[1]);
    }
    {
      const float4* p = (const float4*)(b1 + ko);
      bfr[1] = cvt8(p[0], p[1]);
    }
    af[0] = *(const bf16x8*)(a0 + ko);
    af[1] = *(const bf16x8*)(a1 + ko);
#pragma unroll
    for (int mi = 0; mi < 2; ++mi)
#pragma unroll
      for (int jn = 0; jn < 2; ++jn)
        acc[mi][jn] = __builtin_amdgcn_mfma_f32_16x16x32_bf16(
            af[mi], bfr[jn], acc[mi][jn], 0, 0, 0);
  }

#pragma unroll
  for (int mi = 0; mi < 2; ++mi)
#pragma unroll
    for (int jn = 0; jn < 2; ++jn) {
      int vv = vb + (wn * 2 + jn) * 16 + l15;
      float bias = fc_b[vv];
#pragma unroll
      for (int rr = 0; rr < 4; ++rr) {
        int bb = (wm * 2 + mi) * 16 + lq * 4 + rr;
        out[(size_t)bb * 32000 + vv] = acc[mi][jn][rr] + bias;
      }
    }
}

extern "C" void kernel_launch(void* const* d_in, const int* in_sizes, int n_in,
                              void* d_out, int out_size, void* d_ws,
                              size_t ws_size, hipStream_t stream) {
  const int* ids = (const int*)d_in[0];
  const float* h0 = (const float*)d_in[1];
  const float* c0 = (const float*)d_in[2];
  const float* enc = (const float*)d_in[3];
  const float* emb = (const float*)d_in[4];
  const float* attn_W = (const float*)d_in[5];
  const float* attn_b = (const float*)d_in[6];
  const float* vvec = (const float*)d_in[7];
  const float* W_ih = (const float*)d_in[8];
  const float* W_hh = (const float*)d_in[9];
  const float* b_ih = (const float*)d_in[10];
  const float* b_hh = (const float*)d_in[11];
  const float* fc_W = (const float*)d_in[12];
  const float* fc_b = (const float*)d_in[13];
  float* out = (float*)d_out;
  char* ws = (char*)d_ws;

  bf16* Wp = (bf16*)ws;                     // 512*1024*2    = 1048576
  bf16* Acat = (bf16*)(ws + 1048576);       // 128*1536*2    = 393216
  bf16* hnewb = (bf16*)(ws + 1441792);      // 128*512*2     = 131072
  float* gates = (float*)(ws + 1572864);    // 128*2048*4    = 1048576

  k_pack<<<128, 512, 0, stream>>>(attn_W, Wp);
  k_attn<<<128, 512, 0, stream>>>(enc, Wp, attn_b, vvec, emb, ids, h0, Acat, gates);
  k_gates<<<dim3(32, 6), 512, 0, stream>>>(Acat, W_ih, W_hh, gates);
  k_cell<<<128, 512, 0, stream>>>(gates, b_ih, b_hh, c0, out, hnewb);
  k_fc<<<500, 512, 0, stream>>>(hnewb, fc_W, fc_b, out);
}

// Round 4
// 244.780 us; speedup vs baseline: 1.0415x; 1.0415x over previous
//
#include <hip/hip_runtime.h>

typedef __bf16 bf16;
typedef __bf16 bf16x8 __attribute__((ext_vector_type(8)));
typedef float f32x4 __attribute__((ext_vector_type(4)));

#define VOCAB 32000
#define HID 512
#define BATCH 128
#define SEQ 64

__device__ inline bf16x8 cvt8(float4 a, float4 b) {
  bf16x8 r;
  r[0] = (bf16)a.x; r[1] = (bf16)a.y; r[2] = (bf16)a.z; r[3] = (bf16)a.w;
  r[4] = (bf16)b.x; r[5] = (bf16)b.y; r[6] = (bf16)b.z; r[7] = (bf16)b.w;
  return r;
}

__device__ inline float fast_tanh(float x) {
  x = fminf(fmaxf(x, -15.f), 15.f);
  float e = __expf(2.f * x);
  return (e - 1.f) / (e + 1.f);
}
__device__ inline float fast_sig(float x) {
  return 1.f / (1.f + __expf(-x));
}

// ---------------------------------------------------------------------------
// Kernel 1: pack FULL attn_W (512 x 1024 fp32) -> bf16 MFMA-B-operand order.
// ---------------------------------------------------------------------------
__global__ __launch_bounds__(512) void k_pack(
    const float* __restrict__ attn_W, bf16* __restrict__ Wp) {
  int gid = blockIdx.x * 512 + threadIdx.x;  // 0..65535
  int hh = gid >> 7;                         // row h
  int kc8 = gid & 127;                       // 8-group of k
  const float* src = attn_W + (size_t)hh * 1024 + kc8 * 8;
  bf16x8 v = cvt8(((const float4*)src)[0], ((const float4*)src)[1]);
  int kchunk = kc8 >> 2, klane = kc8 & 3;
  int ntile = hh >> 4, nlane = hh & 15;
  int lane = klane * 16 + nlane;
  *(bf16x8*)(Wp + ((size_t)(kchunk * 32 + ntile) * 64 + lane) * 8) = v;
}

// ---------------------------------------------------------------------------
// Kernel 2: per-batch fused attention (e1 folded in as K=1024 GEMM).
// ---------------------------------------------------------------------------
__global__ __launch_bounds__(512) void k_attn(
    const float* __restrict__ enc, const bf16* __restrict__ Wp,
    const float* __restrict__ attn_b, const float* __restrict__ vvec,
    const float* __restrict__ emb, const int* __restrict__ ids,
    const float* __restrict__ h0, bf16* __restrict__ Acat,
    float* __restrict__ gates_ws) {
  __shared__ char smem[65536];
  __shared__ bf16 h0s[512];
  bf16* encA = (bf16*)smem;                 // phase 1: 64x512 bf16 (swizzled)
  float* spart = (float*)smem;              // phase 2: 8x64
  float* wgt = (float*)(smem + 2048);       // 64
  float* ctxp = (float*)(smem + 2304);      // 8x512

  int b = blockIdx.x, tid = threadIdx.x;
  int w = tid >> 6, lane = tid & 63;
  int l15 = lane & 15, lq = lane >> 4;
  const float* encb = enc + (size_t)b * SEQ * HID;

  // zero the gates accumulator
  {
    int gid = b * 512 + tid;
    float4 z = {0.f, 0.f, 0.f, 0.f};
    ((float4*)gates_ws)[gid] = z;
  }

  h0s[tid] = (bf16)h0[b * 512 + tid];

  // stage enc[b] -> bf16 LDS, XOR-swizzled
#pragma unroll
  for (int i = 0; i < 8; ++i) {
    int cl = tid + i * 512;
    int row = cl >> 6;
    int c = cl & 63;
    int phys = c ^ (row & 7);
    const float4* src = (const float4*)(encb + row * 512 + c * 8);
    bf16x8 v = cvt8(src[0], src[1]);
    *(bf16x8*)(encA + row * 512 + phys * 8) = v;
  }
  __syncthreads();

  f32x4 acc[4][4];
  f32x4 acc_e1[4];
#pragma unroll
  for (int mt = 0; mt < 4; ++mt)
#pragma unroll
    for (int jn = 0; jn < 4; ++jn) acc[mt][jn] = (f32x4)0.f;
#pragma unroll
  for (int jn = 0; jn < 4; ++jn) acc_e1[jn] = (f32x4)0.f;

  // h0 half: kchunks 0..15 (attn_W cols 0..511), row-invariant accumulator
#pragma unroll 4
  for (int kc = 0; kc < 16; ++kc) {
    bf16x8 af = *(const bf16x8*)(h0s + kc * 32 + lq * 8);
#pragma unroll
    for (int jn = 0; jn < 4; ++jn) {
      int nt = w * 4 + jn;
      bf16x8 bfr = *(const bf16x8*)(Wp + ((size_t)(kc * 32 + nt) * 64 + lane) * 8);
      acc_e1[jn] = __builtin_amdgcn_mfma_f32_16x16x32_bf16(af, bfr, acc_e1[jn], 0, 0, 0);
    }
  }

  // enc half: kchunks 16..31 (attn_W cols 512..1023)
#pragma unroll 2
  for (int kc = 16; kc < 32; ++kc) {
    bf16x8 bfr[4], af[4];
#pragma unroll
    for (int jn = 0; jn < 4; ++jn) {
      int nt = w * 4 + jn;
      bfr[jn] = *(const bf16x8*)(Wp + ((size_t)(kc * 32 + nt) * 64 + lane) * 8);
    }
#pragma unroll
    for (int mt = 0; mt < 4; ++mt) {
      int row = mt * 16 + l15;
      int c = (kc - 16) * 4 + lq;
      int phys = c ^ (row & 7);
      af[mt] = *(const bf16x8*)(encA + row * 512 + phys * 8);
    }
#pragma unroll
    for (int mt = 0; mt < 4; ++mt)
#pragma unroll
      for (int jn = 0; jn < 4; ++jn)
        acc[mt][jn] = __builtin_amdgcn_mfma_f32_16x16x32_bf16(
            af[mt], bfr[jn], acc[mt][jn], 0, 0, 0);
  }
  __syncthreads();  // encA dead; smem reused

  // epilogue: scores
  float p[4][4];
#pragma unroll
  for (int mt = 0; mt < 4; ++mt)
#pragma unroll
    for (int r = 0; r < 4; ++r) p[mt][r] = 0.f;
#pragma unroll
  for (int jn = 0; jn < 4; ++jn) {
    int h = (w * 4 + jn) * 16 + l15;
    float bias = attn_b[h];
    float vv = vvec[h];
#pragma unroll
    for (int mt = 0; mt < 4; ++mt)
#pragma unroll
      for (int r = 0; r < 4; ++r)
        p[mt][r] += vv * fast_tanh(acc[mt][jn][r] + acc_e1[jn][r] + bias);
  }
#pragma unroll
  for (int mt = 0; mt < 4; ++mt)
#pragma unroll
    for (int r = 0; r < 4; ++r) {
      float x = p[mt][r];
      x += __shfl_xor(x, 1);
      x += __shfl_xor(x, 2);
      x += __shfl_xor(x, 4);
      x += __shfl_xor(x, 8);
      p[mt][r] = x;
    }
  if (l15 == 0) {
#pragma unroll
    for (int mt = 0; mt < 4; ++mt)
#pragma unroll
      for (int r = 0; r < 4; ++r) {
        int s = mt * 16 + lq * 4 + r;
        spart[w * 64 + s] = p[mt][r];
      }
  }
  __syncthreads();

  // softmax over s (wave 0)
  if (tid < 64) {
    float sc = 0.f;
#pragma unroll
    for (int ww = 0; ww < 8; ++ww) sc += spart[ww * 64 + tid];
    float mx = sc;
    for (int m = 32; m; m >>= 1) mx = fmaxf(mx, __shfl_xor(mx, m));
    float e = __expf(sc - mx);
    float sm = e;
    for (int m = 32; m; m >>= 1) sm += __shfl_xor(sm, m);
    wgt[tid] = e / sm;
  }
  __syncthreads();

  // context
  {
    int hc = tid & 63, sg = tid >> 6;
    float a8[8];
#pragma unroll
    for (int j = 0; j < 8; ++j) a8[j] = 0.f;
    for (int s = sg * 8; s < sg * 8 + 8; ++s) {
      float wv = wgt[s];
      const float4* src = (const float4*)(encb + s * 512 + hc * 8);
      float4 x0 = src[0], x1 = src[1];
      a8[0] += wv * x0.x; a8[1] += wv * x0.y; a8[2] += wv * x0.z; a8[3] += wv * x0.w;
      a8[4] += wv * x1.x; a8[5] += wv * x1.y; a8[6] += wv * x1.z; a8[7] += wv * x1.w;
    }
#pragma unroll
    for (int j = 0; j < 8; ++j) ctxp[sg * 512 + hc * 8 + j] = a8[j];
  }
  __syncthreads();

  {
    int h = tid;
    float c = 0.f;
#pragma unroll
    for (int g = 0; g < 8; ++g) c += ctxp[g * 512 + h];
    int id = ids[b];
    Acat[(size_t)b * 1536 + h] = (bf16)emb[(size_t)id * 512 + h];
    Acat[(size_t)b * 1536 + 512 + h] = (bf16)c;
    Acat[(size_t)b * 1536 + 1024 + h] = (bf16)h0[b * 512 + h];
  }
}

// ---------------------------------------------------------------------------
// Kernel 3: gates partial GEMM, SINGLE-BARRIER. grid (32 n-tiles, 6 ks).
//   Bulk-stage 64 rows x 256 cols fp32 -> bf16 LDS (XOR-swizzled, coalesced
//   32 B/thread bursts), one __syncthreads, then barrier-free MFMA phase.
// ---------------------------------------------------------------------------
__global__ __launch_bounds__(512) void k_gates(
    const bf16* __restrict__ Acat, const float* __restrict__ W_ih,
    const float* __restrict__ W_hh, float* __restrict__ gates_ws) {
  int nb = blockIdx.x, ks = blockIdx.y;
  __shared__ bf16 Wl[64 * 256];  // 32 KB: rows of 256 bf16, 32 chunks of 16 B
  int tid = threadIdx.x, w = tid >> 6, lane = tid & 63;
  int l15 = lane & 15, lq = lane >> 4;
  int wm = w >> 1, wn = w & 1;  // wave: mtiles {2wm,2wm+1}, ntiles {2wn,2wn+1}

  // stage: 64 rows x 32 chunks (16 B bf16 = 32 B fp32 each) = 2048 chunks
#pragma unroll
  for (int i = 0; i < 4; ++i) {
    int g = i * 512 + tid;
    int row = g >> 5, c = g & 31;
    int kcol = ks * 256 + c * 8;
    int grow = nb * 64 + row;
    const float4* p = (ks < 4)
        ? (const float4*)(W_ih + (size_t)grow * 1024 + kcol)
        : (const float4*)(W_hh + (size_t)grow * 512 + (kcol - 1024));
    int phys = c ^ (row & 7);
    *(bf16x8*)(Wl + row * 256 + phys * 8) = cvt8(p[0], p[1]);
  }
  __syncthreads();

  f32x4 acc[2][2];
#pragma unroll
  for (int i = 0; i < 2; ++i)
#pragma unroll
    for (int j = 0; j < 2; ++j) acc[i][j] = (f32x4)0.f;

#pragma unroll 4
  for (int kt = 0; kt < 8; ++kt) {
    int ko = ks * 256 + kt * 32 + lq * 8;
    bf16x8 bfr[2], af[2];
#pragma unroll
    for (int jn = 0; jn < 2; ++jn) {
      int row = (wn * 2 + jn) * 16 + l15;
      int c = kt * 4 + lq;
      int phys = c ^ (row & 7);
      bfr[jn] = *(const bf16x8*)(Wl + row * 256 + phys * 8);
    }
#pragma unroll
    for (int mi = 0; mi < 2; ++mi) {
      int m = (wm * 2 + mi) * 16 + l15;
      af[mi] = *(const bf16x8*)(Acat + (size_t)m * 1536 + ko);
    }
#pragma unroll
    for (int mi = 0; mi < 2; ++mi)
#pragma unroll
      for (int jn = 0; jn < 2; ++jn)
        acc[mi][jn] = __builtin_amdgcn_mfma_f32_16x16x32_bf16(
            af[mi], bfr[jn], acc[mi][jn], 0, 0, 0);
  }
#pragma unroll
  for (int mi = 0; mi < 2; ++mi)
#pragma unroll
    for (int jn = 0; jn < 2; ++jn)
#pragma unroll
      for (int rr = 0; rr < 4; ++rr) {
        int bb = (wm * 2 + mi) * 16 + lq * 4 + rr;
        int n = nb * 64 + (wn * 2 + jn) * 16 + l15;
        atomicAdd(&gates_ws[(size_t)bb * 2048 + n], acc[mi][jn][rr]);
      }
}

// ---------------------------------------------------------------------------
// Kernel 4: elementwise LSTM cell.
// ---------------------------------------------------------------------------
__global__ __launch_bounds__(512) void k_cell(
    const float* __restrict__ gates_ws, const float* __restrict__ b_ih,
    const float* __restrict__ b_hh, const float* __restrict__ c0,
    float* __restrict__ out, bf16* __restrict__ hnewb) {
  int idx = blockIdx.x * 512 + threadIdx.x;  // 0..65535
  int b = idx >> 9, h = idx & 511;
  const float* g = gates_ws + (size_t)b * 2048;
  float iv = g[h] + b_ih[h] + b_hh[h];
  float fv = g[512 + h] + b_ih[512 + h] + b_hh[512 + h];
  float gv = g[1024 + h] + b_ih[1024 + h] + b_hh[1024 + h];
  float ov = g[1536 + h] + b_ih[1536 + h] + b_hh[1536 + h];
  float cn = fast_sig(fv) * c0[idx] + fast_sig(iv) * fast_tanh(gv);
  float hn = fast_sig(ov) * fast_tanh(cn);
  out[4096000 + idx] = hn;
  out[4096000 + 65536 + idx] = cn;
  hnewb[idx] = (bf16)hn;
}

// ---------------------------------------------------------------------------
// Kernel 5: FC, SINGLE-BARRIER. 1000 blocks x 32 vocab rows.
//   Bulk-stage 32 rows x 512 cols fp32 -> bf16 LDS (XOR-swizzled; global
//   reads are contiguous 32 B/thread, all in flight at once -> one vmcnt
//   drain per block), one __syncthreads, then barrier-free MFMA phase.
//   32 KB LDS + low VGPR -> 4 blocks/CU: 4 overlapping staging streams.
// ---------------------------------------------------------------------------
__global__ __launch_bounds__(512) void k_fc(
    const bf16* __restrict__ hnewb, const float* __restrict__ fc_W,
    const float* __restrict__ fc_b, float* __restrict__ out) {
  int vb = blockIdx.x * 32;
  __shared__ bf16 Wl[32 * 512];  // 32 KB: rows of 512 bf16, 64 chunks of 16 B
  int tid = threadIdx.x, w = tid >> 6, lane = tid & 63;
  int l15 = lane & 15, lq = lane >> 4;
  int wm = w >> 1, wn = w & 1;  // wave: mtiles {2wm,2wm+1}, ntile wn

  // stage: 32 rows x 64 chunks = 2048 chunks, 4 per thread, coalesced
#pragma unroll
  for (int i = 0; i < 4; ++i) {
    int g = i * 512 + tid;
    int row = g >> 6, c = g & 63;
    const float4* p = (const float4*)(fc_W + (size_t)(vb + row) * 512 + c * 8);
    int phys = c ^ (row & 7);
    *(bf16x8*)(Wl + row * 512 + phys * 8) = cvt8(p[0], p[1]);
  }
  __syncthreads();

  f32x4 acc[2];
  acc[0] = (f32x4)0.f;
  acc[1] = (f32x4)0.f;

  const bf16* a0 = hnewb + (size_t)((wm * 2 + 0) * 16 + l15) * 512 + lq * 8;
  const bf16* a1 = hnewb + (size_t)((wm * 2 + 1) * 16 + l15) * 512 + lq * 8;
  int browbase = wn * 16 + l15;

#pragma unroll 4
  for (int kt = 0; kt < 16; ++kt) {
    int c = kt * 4 + lq;
    int phys = c ^ (browbase & 7);
    bf16x8 bfr = *(const bf16x8*)(Wl + browbase * 512 + phys * 8);
    bf16x8 af0 = *(const bf16x8*)(a0 + kt * 32);
    bf16x8 af1 = *(const bf16x8*)(a1 + kt * 32);
    acc[0] = __builtin_amdgcn_mfma_f32_16x16x32_bf16(af0, bfr, acc[0], 0, 0, 0);
    acc[1] = __builtin_amdgcn_mfma_f32_16x16x32_bf16(af1, bfr, acc[1], 0, 0, 0);
  }

  int vv = vb + wn * 16 + l15;
  float bias = fc_b[vv];
#pragma unroll
  for (int mi = 0; mi < 2; ++mi)
#pragma unroll
    for (int rr = 0; rr < 4; ++rr) {
      int bb = (wm * 2 + mi) * 16 + lq * 4 + rr;
      out[(size_t)bb * 32000 + vv] = acc[mi][rr] + bias;
    }
}

extern "C" void kernel_launch(void* const* d_in, const int* in_sizes, int n_in,
                              void* d_out, int out_size, void* d_ws,
                              size_t ws_size, hipStream_t stream) {
  const int* ids = (const int*)d_in[0];
  const float* h0 = (const float*)d_in[1];
  const float* c0 = (const float*)d_in[2];
  const float* enc = (const float*)d_in[3];
  const float* emb = (const float*)d_in[4];
  const float* attn_W = (const float*)d_in[5];
  const float* attn_b = (const float*)d_in[6];
  const float* vvec = (const float*)d_in[7];
  const float* W_ih = (const float*)d_in[8];
  const float* W_hh = (const float*)d_in[9];
  const float* b_ih = (const float*)d_in[10];
  const float* b_hh = (const float*)d_in[11];
  const float* fc_W = (const float*)d_in[12];
  const float* fc_b = (const float*)d_in[13];
  float* out = (float*)d_out;
  char* ws = (char*)d_ws;

  bf16* Wp = (bf16*)ws;                     // 512*1024*2    = 1048576
  bf16* Acat = (bf16*)(ws + 1048576);       // 128*1536*2    = 393216
  bf16* hnewb = (bf16*)(ws + 1441792);      // 128*512*2     = 131072
  float* gates = (float*)(ws + 1572864);    // 128*2048*4    = 1048576

  k_pack<<<128, 512, 0, stream>>>(attn_W, Wp);
  k_attn<<<128, 512, 0, stream>>>(enc, Wp, attn_b, vvec, emb, ids, h0, Acat, gates);
  k_gates<<<dim3(32, 6), 512, 0, stream>>>(Acat, W_ih, W_hh, gates);
  k_cell<<<128, 512, 0, stream>>>(gates, b_ih, b_hh, c0, out, hnewb);
  k_fc<<<1000, 512, 0, stream>>>(hnewb, fc_W, fc_b, out);
}